// Round 8
// baseline (161.595 us; speedup 1.0000x reference)
//
#include <hip/hip_runtime.h>
#include <hip/hip_bf16.h>

// LinMHA via full algebraic collapse:
//   M~_b = v_b^T k_b                  (512x512 per batch, bf16 MFMA, split-K=16, bf16 partials)
//   P_b  = Wk @ M~_b^T
//   G_bh = SCALE^2 * P_bh @ Wv_h^T
//   Wc_b = Wq^T blockdiag(G_b) Wo^T
//   Out  = q @ Wc_b + b_o
// Both big GEMMs: 2-deep register prefetch (two named reg sets, unroll-by-2 so
// LDS buffer indices are compile-time; each load set gets ~1.5 steps of latency cover).
// B=4, S=8192, C=512, H=8, DK=64.

typedef __attribute__((ext_vector_type(4))) float f32x4;
typedef __attribute__((ext_vector_type(8))) short short8;

#define DEVI __device__ __forceinline__

DEVI unsigned short f2bf(float f) {
  unsigned int u = __builtin_bit_cast(unsigned int, f);
  u += 0x7fffu + ((u >> 16) & 1u);   // RNE
  return (unsigned short)(u >> 16);
}
DEVI float bf2f(unsigned short s) {
  unsigned int u = ((unsigned int)s) << 16;
  return __builtin_bit_cast(float, u);
}
DEVI short8 pack8(f32x4 a, f32x4 b) {
  short8 r;
#pragma unroll
  for (int i = 0; i < 4; ++i) { r[i] = (short)f2bf(a[i]); r[i + 4] = (short)f2bf(b[i]); }
  return r;
}

// ---------------- K1: M~ partials = v^T k over s-chunks (bf16 MFMA, 2-deep pipeline) ----------------
__global__ __launch_bounds__(256, 2) void bigm_kernel(const float* __restrict__ kmat,
                                                      const float* __restrict__ vmat,
                                                      unsigned short* __restrict__ Mpart) {
  __shared__ __align__(16) unsigned short Vt[2][128 * 40];
  __shared__ __align__(16) unsigned short Kt[2][128 * 40];
  const int t = threadIdx.x;
  const int bid = blockIdx.x;
  const int xcd = bid & 7, jj = bid >> 3;      // jj 0..127
  const int p = ((jj >> 4) << 3) | xcd;        // 0..63 = b*16+split, XCD-pinned
  const int tile = jj & 15;
  const int b = p >> 4, split = p & 15;
  const int ti = tile >> 2, tj = tile & 3;
  const int cp0 = ti * 128, ck0 = tj * 128;    // c' tile (v-cols), c tile (k-cols)

  const int lane = t & 63, w = t >> 6;
  const int fr = lane & 15, fg = lane >> 4;
  const int wm = (w >> 1) * 64, wn = (w & 1) * 64;

  // staging: half = t>>7 (0:V, 1:K); u = t&127: cg = c-group (4 c), sg = s-group (8 s)
  const int half = t >> 7;
  const int u = t & 127;
  const int cg = u & 31, sg = u >> 5;
  const float* srcg = (half ? kmat : vmat)
                    + ((size_t)b * 8192 + (size_t)split * 512) * 512
                    + (half ? ck0 : cp0) + cg * 4;
  unsigned short* dstl = (half ? &Kt[0][0] : &Vt[0][0]);
  const int wbase = cg * 4 * 40 + ((sg ^ (cg & 3)) << 3);  // XOR-swizzled granule (R5-validated)

  f32x4 rA[8], rB[8];
  auto gloadA = [&](int sbase) {
    const float* pp = srcg + (size_t)(sbase + sg * 8) * 512;
#pragma unroll
    for (int j = 0; j < 8; ++j) rA[j] = *(const f32x4*)(pp + j * 512);
  };
  auto gloadB = [&](int sbase) {
    const float* pp = srcg + (size_t)(sbase + sg * 8) * 512;
#pragma unroll
    for (int j = 0; j < 8; ++j) rB[j] = *(const f32x4*)(pp + j * 512);
  };
  auto lwriteA = [&](int buf) {
    unsigned short* d = dstl + buf * (128 * 40) + wbase;
#pragma unroll
    for (int ci = 0; ci < 4; ++ci) {
      short8 wv;
#pragma unroll
      for (int j = 0; j < 8; ++j) wv[j] = (short)f2bf(rA[j][ci]);
      *(short8*)(d + ci * 40) = wv;
    }
  };
  auto lwriteB = [&](int buf) {
    unsigned short* d = dstl + buf * (128 * 40) + wbase;
#pragma unroll
    for (int ci = 0; ci < 4; ++ci) {
      short8 wv;
#pragma unroll
      for (int j = 0; j < 8; ++j) wv[j] = (short)f2bf(rB[j][ci]);
      *(short8*)(d + ci * 40) = wv;
    }
  };

  f32x4 acc[4][4] = {};
  const int key = fr >> 2;  // read-side swizzle key
  auto mfma_phase = [&](int cbuf) {
    short8 fa[4], fb[4];
#pragma unroll
    for (int i = 0; i < 4; ++i) {
      fa[i] = *(const short8*)&Vt[cbuf][(wm + i * 16 + fr) * 40 + ((fg ^ key) << 3)];
      fb[i] = *(const short8*)&Kt[cbuf][(wn + i * 16 + fr) * 40 + ((fg ^ key) << 3)];
    }
#pragma unroll
    for (int i = 0; i < 4; ++i)
#pragma unroll
      for (int j = 0; j < 4; ++j)
        acc[i][j] = __builtin_amdgcn_mfma_f32_16x16x32_bf16(fa[i], fb[j], acc[i][j], 0, 0, 0);
  };

  // prologue: step0 -> LDS0; step1 -> regsB
  gloadA(0);
  lwriteA(0);
  gloadB(32);
  __syncthreads();

  for (int it = 0; it < 8; ++it) {
    const int s0 = it * 2;
    // even step s0: compute buf0
    if (it < 7) gloadA((s0 + 2) * 32);
    mfma_phase(0);
    lwriteB(1);                 // step s0+1 -> buf1 (loads had ~1.5 steps of cover)
    __syncthreads();
    // odd step s0+1: compute buf1
    if (it < 7) gloadB((s0 + 3) * 32);
    mfma_phase(1);
    if (it < 7) lwriteA(0);     // step s0+2 -> buf0
    __syncthreads();
  }

  // acc[i][j]: row = c' (A=Vt row), col = c (B=Kt row)
  unsigned short* gp = Mpart + (size_t)p * 262144;
#pragma unroll
  for (int i = 0; i < 4; ++i)
#pragma unroll
    for (int j = 0; j < 4; ++j)
#pragma unroll
      for (int r2 = 0; r2 < 4; ++r2)
        gp[(size_t)(cp0 + wm + i * 16 + fg * 4 + r2) * 512 + ck0 + wn + j * 16 + fr] =
            f2bf(acc[i][j][r2]);
}

// ---------------- K2: Msum = sum_splits Mpart(bf16) -> bf16 [b][c'][c] ----------------
__global__ __launch_bounds__(256) void mred_kernel(const unsigned short* __restrict__ Mpart,
                                                   unsigned short* __restrict__ Msum) {
  const int base = (blockIdx.x * 256 + threadIdx.x) * 8;  // 1048576 total elems
  const int b = base >> 18;
  const int r = base & 262143;
  const unsigned short* src = Mpart + (size_t)(b * 16) * 262144 + r;
  float s[8] = {};
#pragma unroll
  for (int c = 0; c < 16; ++c) {
    short8 u = *(const short8*)(src + (size_t)c * 262144);
#pragma unroll
    for (int j = 0; j < 8; ++j) s[j] += bf2f((unsigned short)u[j]);
  }
  short8 o;
#pragma unroll
  for (int j = 0; j < 8; ++j) o[j] = (short)f2bf(s[j]);
  *(short8*)(Msum + base) = o;
}

// ---------------- K3: P_b[hd][c'] = sum_c Wk[hd][c] * Msum_b[c'][c] -> bf16 ----------------
__global__ __launch_bounds__(256, 3) void stepa_kernel(const float* __restrict__ Wk,
                                                       const unsigned short* __restrict__ Msum,
                                                       unsigned short* __restrict__ P) {
  __shared__ __align__(16) unsigned short Ab[2][128 * 40];
  __shared__ __align__(16) unsigned short Bb[2][128 * 40];
  const int t = threadIdx.x;
  const int n0 = blockIdx.x * 128;   // c'
  const int m0 = blockIdx.y * 128;   // hd
  const int b = blockIdx.z;
  const int lane = t & 63, w = t >> 6;
  const int wm = (w >> 1) * 64, wn = (w & 1) * 64;
  const int fr = lane & 15, fg = lane >> 4;
  const int sr = t >> 2;
  const int sk = (t & 3) * 8;

  const float* pAg = Wk + (size_t)(m0 + sr) * 512 + sk;
  const unsigned short* pBg = Msum + (size_t)b * 262144 + (size_t)(n0 + sr) * 512 + sk;

  f32x4 acc[4][4] = {};
  f32x4 a0, a1, a2, a3;
  short8 sb0, sb1;

  a0 = *(const f32x4*)(pAg);         a1 = *(const f32x4*)(pAg + 4);
  a2 = *(const f32x4*)(pAg + 32768); a3 = *(const f32x4*)(pAg + 32772);
  sb0 = *(const short8*)(pBg);
  sb1 = *(const short8*)(pBg + 32768);
  *(short8*)&Ab[0][sr * 40 + sk] = pack8(a0, a1);
  *(short8*)&Ab[0][(sr + 64) * 40 + sk] = pack8(a2, a3);
  *(short8*)&Bb[0][sr * 40 + sk] = sb0;
  *(short8*)&Bb[0][(sr + 64) * 40 + sk] = sb1;
  __syncthreads();

  for (int step = 0; step < 16; ++step) {
    const int cur = step & 1;
    if (step < 15) {
      const int k1 = (step + 1) * 32;
      a0 = *(const f32x4*)(pAg + k1);         a1 = *(const f32x4*)(pAg + k1 + 4);
      a2 = *(const f32x4*)(pAg + k1 + 32768); a3 = *(const f32x4*)(pAg + k1 + 32772);
      sb0 = *(const short8*)(pBg + k1);
      sb1 = *(const short8*)(pBg + k1 + 32768);
    }
    short8 afr[4], bfr[4];
#pragma unroll
    for (int i = 0; i < 4; ++i) {
      afr[i] = *(const short8*)&Ab[cur][(wm + i * 16 + fr) * 40 + fg * 8];
      bfr[i] = *(const short8*)&Bb[cur][(wn + i * 16 + fr) * 40 + fg * 8];
    }
#pragma unroll
    for (int i = 0; i < 4; ++i)
#pragma unroll
      for (int j = 0; j < 4; ++j)
        acc[i][j] = __builtin_amdgcn_mfma_f32_16x16x32_bf16(afr[i], bfr[j], acc[i][j], 0, 0, 0);
    if (step < 15) {
      const int nxt = cur ^ 1;
      *(short8*)&Ab[nxt][sr * 40 + sk] = pack8(a0, a1);
      *(short8*)&Ab[nxt][(sr + 64) * 40 + sk] = pack8(a2, a3);
      *(short8*)&Bb[nxt][sr * 40 + sk] = sb0;
      *(short8*)&Bb[nxt][(sr + 64) * 40 + sk] = sb1;
    }
    __syncthreads();
  }
#pragma unroll
  for (int i = 0; i < 4; ++i)
#pragma unroll
    for (int j = 0; j < 4; ++j)
#pragma unroll
      for (int r = 0; r < 4; ++r) {
        const int row = m0 + wm + i * 16 + fg * 4 + r;   // hd
        const int col = n0 + wn + j * 16 + fr;           // c'
        P[((size_t)b * 512 + row) * 512 + col] = f2bf(acc[i][j][r]);
      }
}

// ---------------- K4: G[b,h][d][e] = SCALE^2 * sum_c' P[hd][c'] Wv[he][c'] -> f32 ----------------
__global__ __launch_bounds__(64) void stepb_kernel(const unsigned short* __restrict__ P,
                                                   const float* __restrict__ Wv,
                                                   float* __restrict__ Gsum) {
  __shared__ __align__(16) unsigned short Ao[64 * 40];
  __shared__ __align__(16) unsigned short Bo[64 * 40];
  const int t = threadIdx.x;  // 0..63
  const int h = blockIdx.x;
  const int b = blockIdx.y;
  const int fr = t & 15, fg = t >> 4;
  f32x4 acc[4][4] = {};
  for (int step = 0; step < 16; ++step) {
    const int k0 = step * 32;
    const unsigned short* pa = P + ((size_t)b * 512 + h * 64 + t) * 512 + k0;
#pragma unroll
    for (int i = 0; i < 4; ++i) *(short8*)&Ao[t * 40 + i * 8] = *(const short8*)(pa + i * 8);
    const float* pb = Wv + (size_t)(h * 64 + t) * 512 + k0;
#pragma unroll
    for (int i = 0; i < 4; ++i) {
      f32x4 x0 = *(const f32x4*)(pb + i * 8);
      f32x4 x1 = *(const f32x4*)(pb + i * 8 + 4);
      *(short8*)&Bo[t * 40 + i * 8] = pack8(x0, x1);
    }
    __syncthreads();
    short8 afr[4], bfr[4];
#pragma unroll
    for (int i = 0; i < 4; ++i) {
      afr[i] = *(const short8*)&Ao[(i * 16 + fr) * 40 + fg * 8];
      bfr[i] = *(const short8*)&Bo[(i * 16 + fr) * 40 + fg * 8];
    }
#pragma unroll
    for (int i = 0; i < 4; ++i)
#pragma unroll
      for (int j = 0; j < 4; ++j)
        acc[i][j] = __builtin_amdgcn_mfma_f32_16x16x32_bf16(afr[i], bfr[j], acc[i][j], 0, 0, 0);
    __syncthreads();
  }
  float* gout = Gsum + (size_t)(b * 8 + h) * 4096;
#pragma unroll
  for (int i = 0; i < 4; ++i)
#pragma unroll
    for (int j = 0; j < 4; ++j)
#pragma unroll
      for (int r = 0; r < 4; ++r)
        gout[(i * 16 + fg * 4 + r) * 64 + (j * 16 + fr)] = acc[i][j][r] * 0.015625f;  // SCALE^2
}

// ---------------- K5: T3[b][c][h*64+e] = sum_d Wq[h*64+d][c] * G[b,h,d,e] -> bf16 ----------------
__global__ __launch_bounds__(256) void t3_kernel(const float* __restrict__ Wq,
                                                 const float* __restrict__ Gsum,
                                                 unsigned short* __restrict__ T3) {
  __shared__ float Wl[64][64];
  __shared__ float Gl[64][64];
  const int t = threadIdx.x;
  const int c0 = blockIdx.x * 64;
  const int h = blockIdx.y;
  const int b = blockIdx.z;
  const int dd = t >> 2;
  const int c4 = (t & 3) * 16;
  const float* wp = Wq + (size_t)(h * 64 + dd) * 512 + c0 + c4;
  const float* gp = Gsum + (size_t)(b * 8 + h) * 4096 + dd * 64 + c4;
#pragma unroll
  for (int i = 0; i < 4; ++i) {
    *(f32x4*)&Wl[dd][c4 + i * 4] = *(const f32x4*)(wp + i * 4);
    *(f32x4*)&Gl[dd][c4 + i * 4] = *(const f32x4*)(gp + i * 4);
  }
  __syncthreads();
  const int cl0 = (t >> 4) * 4;
  const int e0 = (t & 15) * 4;
  float acc[4][4] = {};
  for (int d = 0; d < 64; ++d) {
    f32x4 wv = *(const f32x4*)&Wl[d][cl0];
    f32x4 gv = *(const f32x4*)&Gl[d][e0];
#pragma unroll
    for (int i = 0; i < 4; ++i)
#pragma unroll
      for (int j = 0; j < 4; ++j)
        acc[i][j] += wv[i] * gv[j];
  }
#pragma unroll
  for (int i = 0; i < 4; ++i)
#pragma unroll
    for (int j = 0; j < 4; ++j)
      T3[((size_t)b * 512 + c0 + cl0 + i) * 512 + h * 64 + e0 + j] = f2bf(acc[i][j]);
}

// ---------------- K6: WcT[b][n][c] = sum_j Wo[n][j] * T3[b][c][j] -> bf16 ----------------
__global__ __launch_bounds__(64) void wc_kernel(const float* __restrict__ Wo,
                                                const unsigned short* __restrict__ T3,
                                                unsigned short* __restrict__ WcT) {
  __shared__ __align__(16) unsigned short Ao[64 * 48];
  __shared__ __align__(16) unsigned short Bo[64 * 48];
  const int t = threadIdx.x;  // 0..63
  const int n0 = blockIdx.x * 64;
  const int c0 = blockIdx.y * 64;
  const int b = blockIdx.z;
  const int fr = t & 15, fg = t >> 4;
  f32x4 acc[4][4] = {};
  for (int step = 0; step < 16; ++step) {
    const int k0 = step * 32;
    const float* pa = Wo + (size_t)(n0 + t) * 512 + k0;
    unsigned short tmp[32];
#pragma unroll
    for (int i = 0; i < 8; ++i) {
      f32x4 vv = *(const f32x4*)(pa + i * 4);
#pragma unroll
      for (int j = 0; j < 4; ++j) tmp[i * 4 + j] = f2bf(vv[j]);
    }
#pragma unroll
    for (int i = 0; i < 4; ++i) *(short8*)&Ao[t * 48 + i * 8] = *(const short8*)&tmp[i * 8];
    const unsigned short* pb = T3 + ((size_t)b * 512 + c0 + t) * 512 + k0;
#pragma unroll
    for (int i = 0; i < 4; ++i) *(short8*)&Bo[t * 48 + i * 8] = *(const short8*)(pb + i * 8);
    __syncthreads();
    short8 afr[4], bfr[4];
#pragma unroll
    for (int i = 0; i < 4; ++i) {
      afr[i] = *(const short8*)&Ao[(i * 16 + fr) * 48 + fg * 8];
      bfr[i] = *(const short8*)&Bo[(i * 16 + fr) * 48 + fg * 8];
    }
#pragma unroll
    for (int i = 0; i < 4; ++i)
#pragma unroll
      for (int j = 0; j < 4; ++j)
        acc[i][j] = __builtin_amdgcn_mfma_f32_16x16x32_bf16(afr[i], bfr[j], acc[i][j], 0, 0, 0);
    __syncthreads();
  }
#pragma unroll
  for (int i = 0; i < 4; ++i)
#pragma unroll
    for (int j = 0; j < 4; ++j)
#pragma unroll
      for (int r = 0; r < 4; ++r)
        WcT[((size_t)b * 512 + n0 + i * 16 + fg * 4 + r) * 512 + c0 + j * 16 + fr] =
            f2bf(acc[i][j][r]);
}

// ---------------- K7: Out = q @ Wc[b] + b_o -> f32 (2-deep pipeline, XCD-grouped) ----------------
__global__ __launch_bounds__(256, 3) void out_kernel(const float* __restrict__ q,
                                                     const unsigned short* __restrict__ WcT,
                                                     const float* __restrict__ bo,
                                                     float* __restrict__ Out) {
  __shared__ __align__(16) unsigned short Ab[2][128 * 40];
  __shared__ __align__(16) unsigned short Bb[2][128 * 40];
  const int t = threadIdx.x;
  const int bid = blockIdx.x;
  const int xcd = bid & 7, idx = bid >> 3;
  const int mt = xcd * 32 + (idx >> 2);
  const int nt = idx & 3;
  const int m0 = mt * 128, n0 = nt * 128;
  const unsigned short* Wc = WcT + ((size_t)(m0 >> 13)) * 512 * 512;  // batch = m0/8192
  const int lane = t & 63, w = t >> 6;
  const int wm = (w >> 1) * 64, wn = (w & 1) * 64;
  const int fr = lane & 15, fg = lane >> 4;
  const int sr = t >> 2;
  const int sk = (t & 3) * 8;

  const float* pAg = q + (size_t)(m0 + sr) * 512 + sk;
  const unsigned short* pBg = Wc + (size_t)(n0 + sr) * 512 + sk;

  f32x4 aA[4], aB[4];
  short8 bA[2], bB[2];
  auto gloadA = [&](int k) {
    aA[0] = *(const f32x4*)(pAg + k);         aA[1] = *(const f32x4*)(pAg + k + 4);
    aA[2] = *(const f32x4*)(pAg + k + 32768); aA[3] = *(const f32x4*)(pAg + k + 32772);
    bA[0] = *(const short8*)(pBg + k);
    bA[1] = *(const short8*)(pBg + k + 32768);
  };
  auto gloadB = [&](int k) {
    aB[0] = *(const f32x4*)(pAg + k);         aB[1] = *(const f32x4*)(pAg + k + 4);
    aB[2] = *(const f32x4*)(pAg + k + 32768); aB[3] = *(const f32x4*)(pAg + k + 32772);
    bB[0] = *(const short8*)(pBg + k);
    bB[1] = *(const short8*)(pBg + k + 32768);
  };
  auto lwriteA = [&](int buf) {
    *(short8*)&Ab[buf][sr * 40 + sk] = pack8(aA[0], aA[1]);
    *(short8*)&Ab[buf][(sr + 64) * 40 + sk] = pack8(aA[2], aA[3]);
    *(short8*)&Bb[buf][sr * 40 + sk] = bA[0];
    *(short8*)&Bb[buf][(sr + 64) * 40 + sk] = bA[1];
  };
  auto lwriteB = [&](int buf) {
    *(short8*)&Ab[buf][sr * 40 + sk] = pack8(aB[0], aB[1]);
    *(short8*)&Ab[buf][(sr + 64) * 40 + sk] = pack8(aB[2], aB[3]);
    *(short8*)&Bb[buf][sr * 40 + sk] = bB[0];
    *(short8*)&Bb[buf][(sr + 64) * 40 + sk] = bB[1];
  };

  f32x4 acc[4][4] = {};
  auto mfma_phase = [&](int cbuf) {
    short8 afr[4], bfr[4];
#pragma unroll
    for (int i = 0; i < 4; ++i) {
      afr[i] = *(const short8*)&Ab[cbuf][(wm + i * 16 + fr) * 40 + fg * 8];
      bfr[i] = *(const short8*)&Bb[cbuf][(wn + i * 16 + fr) * 40 + fg * 8];
    }
#pragma unroll
    for (int i = 0; i < 4; ++i)
#pragma unroll
      for (int j = 0; j < 4; ++j)
        acc[i][j] = __builtin_amdgcn_mfma_f32_16x16x32_bf16(afr[i], bfr[j], acc[i][j], 0, 0, 0);
  };

  // prologue: step0 -> LDS0; step1 -> regsB
  gloadA(0);
  lwriteA(0);
  gloadB(32);
  __syncthreads();

  for (int it = 0; it < 8; ++it) {
    const int s0 = it * 2;
    if (it < 7) gloadA((s0 + 2) * 32);
    mfma_phase(0);
    lwriteB(1);
    __syncthreads();
    if (it < 7) gloadB((s0 + 3) * 32);
    mfma_phase(1);
    if (it < 7) lwriteA(0);
    __syncthreads();
  }

  float bias[4];
#pragma unroll
  for (int j = 0; j < 4; ++j) bias[j] = bo[n0 + wn + j * 16 + fr];
#pragma unroll
  for (int i = 0; i < 4; ++i)
#pragma unroll
    for (int j = 0; j < 4; ++j)
#pragma unroll
      for (int r = 0; r < 4; ++r) {
        const int row = m0 + wm + i * 16 + fg * 4 + r;
        const int col = n0 + wn + j * 16 + fr;
        Out[(size_t)row * 512 + col] = acc[i][j][r] + bias[j];
      }
}

extern "C" void kernel_launch(void* const* d_in, const int* in_sizes, int n_in,
                              void* d_out, int out_size, void* d_ws, size_t ws_size,
                              hipStream_t stream) {
  const float* q  = (const float*)d_in[0];
  const float* k  = (const float*)d_in[1];
  const float* v  = (const float*)d_in[2];
  const float* Wq = (const float*)d_in[3];
  const float* Wk = (const float*)d_in[4];
  const float* Wv = (const float*)d_in[5];
  const float* Wo = (const float*)d_in[6];
  const float* bo = (const float*)d_in[7];
  float* Out = (float*)d_out;

  // Mpart (bf16, 64 partials x 512KB = 32MB) lives in d_out until out_kernel overwrites it.
  unsigned short* Mpart = (unsigned short*)d_out;
  char* ws = (char*)d_ws;
  unsigned short* Msum = (unsigned short*)ws;                          // 2 MB
  unsigned short* P    = (unsigned short*)(ws + (size_t)2 * 1048576);  // 2 MB
  float* Gsum          = (float*)(ws + (size_t)4 * 1048576);           // 0.5 MB
  unsigned short* T3   = (unsigned short*)(ws + (size_t)5 * 1048576);  // 2 MB
  unsigned short* WcT  = (unsigned short*)(ws + (size_t)7 * 1048576);  // 2 MB

  bigm_kernel<<<1024, 256, 0, stream>>>(k, v, Mpart);
  mred_kernel<<<512, 256, 0, stream>>>(Mpart, Msum);
  stepa_kernel<<<dim3(4, 4, 4), 256, 0, stream>>>(Wk, Msum, P);
  stepb_kernel<<<dim3(8, 4), 64, 0, stream>>>(P, Wv, Gsum);
  t3_kernel<<<dim3(8, 8, 4), 256, 0, stream>>>(Wq, Gsum, T3);
  wc_kernel<<<dim3(8, 8, 4), 64, 0, stream>>>(Wo, T3, WcT);
  out_kernel<<<1024, 256, 0, stream>>>(q, WcT, bo, Out);
}

// Round 9
// 157.968 us; speedup vs baseline: 1.0230x; 1.0230x over previous
//
#include <hip/hip_runtime.h>
#include <hip/hip_bf16.h>

// LinMHA via full algebraic collapse:
//   M~_b = v_b^T k_b                  (512x512 per batch, bf16 MFMA, split-K=16, bf16 partials)
//   P_b  = Wk @ M~_b^T
//   G_bh = SCALE^2 * P_bh @ Wv_h^T
//   Wc_b = Wq^T blockdiag(G_b) Wo^T
//   Out  = q @ Wc_b + b_o
// f32->bf16 via native __bf16 cast (gfx950 v_cvt_pk_bf16_f32, RNE, compiler-paired).
// B=4, S=8192, C=512, H=8, DK=64.

typedef __attribute__((ext_vector_type(4))) float f32x4;
typedef __attribute__((ext_vector_type(8))) short short8;

#define DEVI __device__ __forceinline__

DEVI unsigned short f2bf(float f) {
  __bf16 h = (__bf16)f;   // hardware v_cvt_pk_bf16_f32 on gfx950 (RNE)
  return __builtin_bit_cast(unsigned short, h);
}
DEVI float bf2f(unsigned short s) {
  unsigned int u = ((unsigned int)s) << 16;
  return __builtin_bit_cast(float, u);
}
DEVI short8 pack8(f32x4 a, f32x4 b) {
  short8 r;
#pragma unroll
  for (int i = 0; i < 4; ++i) { r[i] = (short)f2bf(a[i]); r[i + 4] = (short)f2bf(b[i]); }
  return r;
}

// ---------------- K1: M~ partials = v^T k over s-chunks (bf16 MFMA, 1-deep, 4 blocks/CU) ----------------
// grid 1024: (b,split) pinned to one XCD (16 tiles of 128x128, 2MB k+v chunk in L2).
// LDS [c][s] pitch 40 shorts, granule XOR-swizzle (R5-validated conflict-free).
__global__ __launch_bounds__(256, 4) void bigm_kernel(const float* __restrict__ kmat,
                                                      const float* __restrict__ vmat,
                                                      unsigned short* __restrict__ Mpart) {
  __shared__ __align__(16) unsigned short Vt[2][128 * 40];
  __shared__ __align__(16) unsigned short Kt[2][128 * 40];
  const int t = threadIdx.x;
  const int bid = blockIdx.x;
  const int xcd = bid & 7, jj = bid >> 3;      // jj 0..127
  const int p = ((jj >> 4) << 3) | xcd;        // 0..63 = b*16+split, XCD-pinned
  const int tile = jj & 15;
  const int b = p >> 4, split = p & 15;
  const int ti = tile >> 2, tj = tile & 3;
  const int cp0 = ti * 128, ck0 = tj * 128;    // c' tile (v-cols), c tile (k-cols)

  const int lane = t & 63, w = t >> 6;
  const int fr = lane & 15, fg = lane >> 4;
  const int wm = (w >> 1) * 64, wn = (w & 1) * 64;

  // staging: half = t>>7 (0:V, 1:K); u = t&127: cg = c-group (4 c), sg = s-group (8 s)
  const int half = t >> 7;
  const int u = t & 127;
  const int cg = u & 31, sg = u >> 5;
  const float* srcg = (half ? kmat : vmat)
                    + ((size_t)b * 8192 + (size_t)split * 512) * 512
                    + (half ? ck0 : cp0) + cg * 4;
  unsigned short* dstl = (half ? &Kt[0][0] : &Vt[0][0]);
  const int wbase = cg * 4 * 40 + ((sg ^ (cg & 3)) << 3);  // XOR-swizzled granule

  f32x4 r[8];
  auto gload = [&](int sbase) {
    const float* pp = srcg + (size_t)(sbase + sg * 8) * 512;
#pragma unroll
    for (int j = 0; j < 8; ++j) r[j] = *(const f32x4*)(pp + j * 512);
  };
  auto lwrite = [&](int buf) {
    unsigned short* d = dstl + buf * (128 * 40) + wbase;
#pragma unroll
    for (int ci = 0; ci < 4; ++ci) {
      short8 wv;
#pragma unroll
      for (int j = 0; j < 8; ++j) wv[j] = (short)f2bf(r[j][ci]);
      *(short8*)(d + ci * 40) = wv;
    }
  };

  f32x4 acc[4][4] = {};

  gload(0);
  lwrite(0);
  __syncthreads();

  const int key = fr >> 2;  // read-side swizzle key = (row>>2)&3
  for (int step = 0; step < 16; ++step) {
    const int cur = step & 1;
    if (step < 15) gload((step + 1) * 32);
    short8 fa[4], fb[4];
#pragma unroll
    for (int i = 0; i < 4; ++i) {
      fa[i] = *(const short8*)&Vt[cur][(wm + i * 16 + fr) * 40 + ((fg ^ key) << 3)];
      fb[i] = *(const short8*)&Kt[cur][(wn + i * 16 + fr) * 40 + ((fg ^ key) << 3)];
    }
#pragma unroll
    for (int i = 0; i < 4; ++i)
#pragma unroll
      for (int j = 0; j < 4; ++j)
        acc[i][j] = __builtin_amdgcn_mfma_f32_16x16x32_bf16(fa[i], fb[j], acc[i][j], 0, 0, 0);
    if (step < 15) lwrite(cur ^ 1);
    __syncthreads();
  }
  // acc[i][j]: row = c' (A=Vt row), col = c (B=Kt row)
  unsigned short* gp = Mpart + (size_t)p * 262144;
#pragma unroll
  for (int i = 0; i < 4; ++i)
#pragma unroll
    for (int j = 0; j < 4; ++j)
#pragma unroll
      for (int r2 = 0; r2 < 4; ++r2)
        gp[(size_t)(cp0 + wm + i * 16 + fg * 4 + r2) * 512 + ck0 + wn + j * 16 + fr] =
            f2bf(acc[i][j][r2]);
}

// ---------------- K2: Msum = sum_splits Mpart(bf16) -> bf16 [b][c'][c] ----------------
__global__ __launch_bounds__(256) void mred_kernel(const unsigned short* __restrict__ Mpart,
                                                   unsigned short* __restrict__ Msum) {
  const int base = (blockIdx.x * 256 + threadIdx.x) * 8;  // 1048576 total elems
  const int b = base >> 18;
  const int r = base & 262143;
  const unsigned short* src = Mpart + (size_t)(b * 16) * 262144 + r;
  float s[8] = {};
#pragma unroll
  for (int c = 0; c < 16; ++c) {
    short8 u = *(const short8*)(src + (size_t)c * 262144);
#pragma unroll
    for (int j = 0; j < 8; ++j) s[j] += bf2f((unsigned short)u[j]);
  }
  short8 o;
#pragma unroll
  for (int j = 0; j < 8; ++j) o[j] = (short)f2bf(s[j]);
  *(short8*)(Msum + base) = o;
}

// ---------------- K3: P_b[hd][c'] = sum_c Wk[hd][c] * Msum_b[c'][c] -> bf16 ----------------
__global__ __launch_bounds__(256, 3) void stepa_kernel(const float* __restrict__ Wk,
                                                       const unsigned short* __restrict__ Msum,
                                                       unsigned short* __restrict__ P) {
  __shared__ __align__(16) unsigned short Ab[2][128 * 40];
  __shared__ __align__(16) unsigned short Bb[2][128 * 40];
  const int t = threadIdx.x;
  const int n0 = blockIdx.x * 128;   // c'
  const int m0 = blockIdx.y * 128;   // hd
  const int b = blockIdx.z;
  const int lane = t & 63, w = t >> 6;
  const int wm = (w >> 1) * 64, wn = (w & 1) * 64;
  const int fr = lane & 15, fg = lane >> 4;
  const int sr = t >> 2;
  const int sk = (t & 3) * 8;

  const float* pAg = Wk + (size_t)(m0 + sr) * 512 + sk;
  const unsigned short* pBg = Msum + (size_t)b * 262144 + (size_t)(n0 + sr) * 512 + sk;

  f32x4 acc[4][4] = {};
  f32x4 a0, a1, a2, a3;
  short8 sb0, sb1;

  a0 = *(const f32x4*)(pAg);         a1 = *(const f32x4*)(pAg + 4);
  a2 = *(const f32x4*)(pAg + 32768); a3 = *(const f32x4*)(pAg + 32772);
  sb0 = *(const short8*)(pBg);
  sb1 = *(const short8*)(pBg + 32768);
  *(short8*)&Ab[0][sr * 40 + sk] = pack8(a0, a1);
  *(short8*)&Ab[0][(sr + 64) * 40 + sk] = pack8(a2, a3);
  *(short8*)&Bb[0][sr * 40 + sk] = sb0;
  *(short8*)&Bb[0][(sr + 64) * 40 + sk] = sb1;
  __syncthreads();

  for (int step = 0; step < 16; ++step) {
    const int cur = step & 1;
    if (step < 15) {
      const int k1 = (step + 1) * 32;
      a0 = *(const f32x4*)(pAg + k1);         a1 = *(const f32x4*)(pAg + k1 + 4);
      a2 = *(const f32x4*)(pAg + k1 + 32768); a3 = *(const f32x4*)(pAg + k1 + 32772);
      sb0 = *(const short8*)(pBg + k1);
      sb1 = *(const short8*)(pBg + k1 + 32768);
    }
    short8 afr[4], bfr[4];
#pragma unroll
    for (int i = 0; i < 4; ++i) {
      afr[i] = *(const short8*)&Ab[cur][(wm + i * 16 + fr) * 40 + fg * 8];
      bfr[i] = *(const short8*)&Bb[cur][(wn + i * 16 + fr) * 40 + fg * 8];
    }
#pragma unroll
    for (int i = 0; i < 4; ++i)
#pragma unroll
      for (int j = 0; j < 4; ++j)
        acc[i][j] = __builtin_amdgcn_mfma_f32_16x16x32_bf16(afr[i], bfr[j], acc[i][j], 0, 0, 0);
    if (step < 15) {
      const int nxt = cur ^ 1;
      *(short8*)&Ab[nxt][sr * 40 + sk] = pack8(a0, a1);
      *(short8*)&Ab[nxt][(sr + 64) * 40 + sk] = pack8(a2, a3);
      *(short8*)&Bb[nxt][sr * 40 + sk] = sb0;
      *(short8*)&Bb[nxt][(sr + 64) * 40 + sk] = sb1;
    }
    __syncthreads();
  }
#pragma unroll
  for (int i = 0; i < 4; ++i)
#pragma unroll
    for (int j = 0; j < 4; ++j)
#pragma unroll
      for (int r = 0; r < 4; ++r) {
        const int row = m0 + wm + i * 16 + fg * 4 + r;   // hd
        const int col = n0 + wn + j * 16 + fr;           // c'
        P[((size_t)b * 512 + row) * 512 + col] = f2bf(acc[i][j][r]);
      }
}

// ---------------- K4: G[b,h][d][e] = SCALE^2 * sum_c' P[hd][c'] Wv[he][c'] -> f32 ----------------
__global__ __launch_bounds__(64) void stepb_kernel(const unsigned short* __restrict__ P,
                                                   const float* __restrict__ Wv,
                                                   float* __restrict__ Gsum) {
  __shared__ __align__(16) unsigned short Ao[64 * 40];
  __shared__ __align__(16) unsigned short Bo[64 * 40];
  const int t = threadIdx.x;  // 0..63
  const int h = blockIdx.x;
  const int b = blockIdx.y;
  const int fr = t & 15, fg = t >> 4;
  f32x4 acc[4][4] = {};
  for (int step = 0; step < 16; ++step) {
    const int k0 = step * 32;
    const unsigned short* pa = P + ((size_t)b * 512 + h * 64 + t) * 512 + k0;
#pragma unroll
    for (int i = 0; i < 4; ++i) *(short8*)&Ao[t * 40 + i * 8] = *(const short8*)(pa + i * 8);
    const float* pb = Wv + (size_t)(h * 64 + t) * 512 + k0;
#pragma unroll
    for (int i = 0; i < 4; ++i) {
      f32x4 x0 = *(const f32x4*)(pb + i * 8);
      f32x4 x1 = *(const f32x4*)(pb + i * 8 + 4);
      *(short8*)&Bo[t * 40 + i * 8] = pack8(x0, x1);
    }
    __syncthreads();
    short8 afr[4], bfr[4];
#pragma unroll
    for (int i = 0; i < 4; ++i) {
      afr[i] = *(const short8*)&Ao[(i * 16 + fr) * 40 + fg * 8];
      bfr[i] = *(const short8*)&Bo[(i * 16 + fr) * 40 + fg * 8];
    }
#pragma unroll
    for (int i = 0; i < 4; ++i)
#pragma unroll
      for (int j = 0; j < 4; ++j)
        acc[i][j] = __builtin_amdgcn_mfma_f32_16x16x32_bf16(afr[i], bfr[j], acc[i][j], 0, 0, 0);
    __syncthreads();
  }
  float* gout = Gsum + (size_t)(b * 8 + h) * 4096;
#pragma unroll
  for (int i = 0; i < 4; ++i)
#pragma unroll
    for (int j = 0; j < 4; ++j)
#pragma unroll
      for (int r = 0; r < 4; ++r)
        gout[(i * 16 + fg * 4 + r) * 64 + (j * 16 + fr)] = acc[i][j][r] * 0.015625f;  // SCALE^2
}

// ---------------- K5: T3[b][c][h*64+e] = sum_d Wq[h*64+d][c] * G[b,h,d,e] -> bf16 ----------------
__global__ __launch_bounds__(256) void t3_kernel(const float* __restrict__ Wq,
                                                 const float* __restrict__ Gsum,
                                                 unsigned short* __restrict__ T3) {
  __shared__ float Wl[64][64];
  __shared__ float Gl[64][64];
  const int t = threadIdx.x;
  const int c0 = blockIdx.x * 64;
  const int h = blockIdx.y;
  const int b = blockIdx.z;
  const int dd = t >> 2;
  const int c4 = (t & 3) * 16;
  const float* wp = Wq + (size_t)(h * 64 + dd) * 512 + c0 + c4;
  const float* gp = Gsum + (size_t)(b * 8 + h) * 4096 + dd * 64 + c4;
#pragma unroll
  for (int i = 0; i < 4; ++i) {
    *(f32x4*)&Wl[dd][c4 + i * 4] = *(const f32x4*)(wp + i * 4);
    *(f32x4*)&Gl[dd][c4 + i * 4] = *(const f32x4*)(gp + i * 4);
  }
  __syncthreads();
  const int cl0 = (t >> 4) * 4;
  const int e0 = (t & 15) * 4;
  float acc[4][4] = {};
  for (int d = 0; d < 64; ++d) {
    f32x4 wv = *(const f32x4*)&Wl[d][cl0];
    f32x4 gv = *(const f32x4*)&Gl[d][e0];
#pragma unroll
    for (int i = 0; i < 4; ++i)
#pragma unroll
      for (int j = 0; j < 4; ++j)
        acc[i][j] += wv[i] * gv[j];
  }
#pragma unroll
  for (int i = 0; i < 4; ++i)
#pragma unroll
    for (int j = 0; j < 4; ++j)
      T3[((size_t)b * 512 + c0 + cl0 + i) * 512 + h * 64 + e0 + j] = f2bf(acc[i][j]);
}

// ---------------- K6: WcT[b][n][c] = sum_j Wo[n][j] * T3[b][c][j] -> bf16 ----------------
__global__ __launch_bounds__(64) void wc_kernel(const float* __restrict__ Wo,
                                                const unsigned short* __restrict__ T3,
                                                unsigned short* __restrict__ WcT) {
  __shared__ __align__(16) unsigned short Ao[64 * 48];
  __shared__ __align__(16) unsigned short Bo[64 * 48];
  const int t = threadIdx.x;  // 0..63
  const int n0 = blockIdx.x * 64;
  const int c0 = blockIdx.y * 64;
  const int b = blockIdx.z;
  const int fr = t & 15, fg = t >> 4;
  f32x4 acc[4][4] = {};
  for (int step = 0; step < 16; ++step) {
    const int k0 = step * 32;
    const float* pa = Wo + (size_t)(n0 + t) * 512 + k0;
    unsigned short tmp[32];
#pragma unroll
    for (int i = 0; i < 8; ++i) {
      f32x4 vv = *(const f32x4*)(pa + i * 4);
#pragma unroll
      for (int j = 0; j < 4; ++j) tmp[i * 4 + j] = f2bf(vv[j]);
    }
#pragma unroll
    for (int i = 0; i < 4; ++i) *(short8*)&Ao[t * 48 + i * 8] = *(const short8*)&tmp[i * 8];
    const unsigned short* pb = T3 + ((size_t)b * 512 + c0 + t) * 512 + k0;
#pragma unroll
    for (int i = 0; i < 4; ++i) *(short8*)&Bo[t * 48 + i * 8] = *(const short8*)(pb + i * 8);
    __syncthreads();
    short8 afr[4], bfr[4];
#pragma unroll
    for (int i = 0; i < 4; ++i) {
      afr[i] = *(const short8*)&Ao[(i * 16 + fr) * 48 + fg * 8];
      bfr[i] = *(const short8*)&Bo[(i * 16 + fr) * 48 + fg * 8];
    }
#pragma unroll
    for (int i = 0; i < 4; ++i)
#pragma unroll
      for (int j = 0; j < 4; ++j)
        acc[i][j] = __builtin_amdgcn_mfma_f32_16x16x32_bf16(afr[i], bfr[j], acc[i][j], 0, 0, 0);
    __syncthreads();
  }
#pragma unroll
  for (int i = 0; i < 4; ++i)
#pragma unroll
    for (int j = 0; j < 4; ++j)
#pragma unroll
      for (int r = 0; r < 4; ++r)
        WcT[((size_t)b * 512 + n0 + i * 16 + fg * 4 + r) * 512 + c0 + j * 16 + fr] =
            f2bf(acc[i][j][r]);
}

// ---------------- K7: Out = q @ Wc[b] + b_o -> f32 (2-deep pipeline, XCD-grouped) ----------------
__global__ __launch_bounds__(256, 3) void out_kernel(const float* __restrict__ q,
                                                     const unsigned short* __restrict__ WcT,
                                                     const float* __restrict__ bo,
                                                     float* __restrict__ Out) {
  __shared__ __align__(16) unsigned short Ab[2][128 * 40];
  __shared__ __align__(16) unsigned short Bb[2][128 * 40];
  const int t = threadIdx.x;
  const int bid = blockIdx.x;
  const int xcd = bid & 7, idx = bid >> 3;
  const int mt = xcd * 32 + (idx >> 2);
  const int nt = idx & 3;
  const int m0 = mt * 128, n0 = nt * 128;
  const unsigned short* Wc = WcT + ((size_t)(m0 >> 13)) * 512 * 512;  // batch = m0/8192
  const int lane = t & 63, w = t >> 6;
  const int wm = (w >> 1) * 64, wn = (w & 1) * 64;
  const int fr = lane & 15, fg = lane >> 4;
  const int sr = t >> 2;
  const int sk = (t & 3) * 8;

  const float* pAg = q + (size_t)(m0 + sr) * 512 + sk;
  const unsigned short* pBg = Wc + (size_t)(n0 + sr) * 512 + sk;

  f32x4 aA[4], aB[4];
  short8 bA[2], bB[2];
  auto gloadA = [&](int k) {
    aA[0] = *(const f32x4*)(pAg + k);         aA[1] = *(const f32x4*)(pAg + k + 4);
    aA[2] = *(const f32x4*)(pAg + k + 32768); aA[3] = *(const f32x4*)(pAg + k + 32772);
    bA[0] = *(const short8*)(pBg + k);
    bA[1] = *(const short8*)(pBg + k + 32768);
  };
  auto gloadB = [&](int k) {
    aB[0] = *(const f32x4*)(pAg + k);         aB[1] = *(const f32x4*)(pAg + k + 4);
    aB[2] = *(const f32x4*)(pAg + k + 32768); aB[3] = *(const f32x4*)(pAg + k + 32772);
    bB[0] = *(const short8*)(pBg + k);
    bB[1] = *(const short8*)(pBg + k + 32768);
  };
  auto lwriteA = [&](int buf) {
    *(short8*)&Ab[buf][sr * 40 + sk] = pack8(aA[0], aA[1]);
    *(short8*)&Ab[buf][(sr + 64) * 40 + sk] = pack8(aA[2], aA[3]);
    *(short8*)&Bb[buf][sr * 40 + sk] = bA[0];
    *(short8*)&Bb[buf][(sr + 64) * 40 + sk] = bA[1];
  };
  auto lwriteB = [&](int buf) {
    *(short8*)&Ab[buf][sr * 40 + sk] = pack8(aB[0], aB[1]);
    *(short8*)&Ab[buf][(sr + 64) * 40 + sk] = pack8(aB[2], aB[3]);
    *(short8*)&Bb[buf][sr * 40 + sk] = bB[0];
    *(short8*)&Bb[buf][(sr + 64) * 40 + sk] = bB[1];
  };

  f32x4 acc[4][4] = {};
  auto mfma_phase = [&](int cbuf) {
    short8 afr[4], bfr[4];
#pragma unroll
    for (int i = 0; i < 4; ++i) {
      afr[i] = *(const short8*)&Ab[cbuf][(wm + i * 16 + fr) * 40 + fg * 8];
      bfr[i] = *(const short8*)&Bb[cbuf][(wn + i * 16 + fr) * 40 + fg * 8];
    }
#pragma unroll
    for (int i = 0; i < 4; ++i)
#pragma unroll
      for (int j = 0; j < 4; ++j)
        acc[i][j] = __builtin_amdgcn_mfma_f32_16x16x32_bf16(afr[i], bfr[j], acc[i][j], 0, 0, 0);
  };

  // prologue: step0 -> LDS0; step1 -> regsB
  gloadA(0);
  lwriteA(0);
  gloadB(32);
  __syncthreads();

  for (int it = 0; it < 8; ++it) {
    const int s0 = it * 2;
    if (it < 7) gloadA((s0 + 2) * 32);
    mfma_phase(0);
    lwriteB(1);
    __syncthreads();
    if (it < 7) gloadB((s0 + 3) * 32);
    mfma_phase(1);
    if (it < 7) lwriteA(0);
    __syncthreads();
  }

  float bias[4];
#pragma unroll
  for (int j = 0; j < 4; ++j) bias[j] = bo[n0 + wn + j * 16 + fr];
#pragma unroll
  for (int i = 0; i < 4; ++i)
#pragma unroll
    for (int j = 0; j < 4; ++j)
#pragma unroll
      for (int r = 0; r < 4; ++r) {
        const int row = m0 + wm + i * 16 + fg * 4 + r;
        const int col = n0 + wn + j * 16 + fr;
        Out[(size_t)row * 512 + col] = acc[i][j][r] + bias[j];
      }
}

extern "C" void kernel_launch(void* const* d_in, const int* in_sizes, int n_in,
                              void* d_out, int out_size, void* d_ws, size_t ws_size,
                              hipStream_t stream) {
  const float* q  = (const float*)d_in[0];
  const float* k  = (const float*)d_in[1];
  const float* v  = (const float*)d_in[2];
  const float* Wq = (const float*)d_in[3];
  const float* Wk = (const float*)d_in[4];
  const float* Wv = (const float*)d_in[5];
  const float* Wo = (const float*)d_in[6];
  const float* bo = (const float*)d_in[7];
  float* Out = (float*)d_out;

  // Mpart (bf16, 64 partials x 512KB = 32MB) lives in d_out until out_kernel overwrites it.
  unsigned short* Mpart = (unsigned short*)d_out;
  char* ws = (char*)d_ws;
  unsigned short* Msum = (unsigned short*)ws;                          // 2 MB
  unsigned short* P    = (unsigned short*)(ws + (size_t)2 * 1048576);  // 2 MB
  float* Gsum          = (float*)(ws + (size_t)4 * 1048576);           // 0.5 MB
  unsigned short* T3   = (unsigned short*)(ws + (size_t)5 * 1048576);  // 2 MB
  unsigned short* WcT  = (unsigned short*)(ws + (size_t)7 * 1048576);  // 2 MB

  bigm_kernel<<<1024, 256, 0, stream>>>(k, v, Mpart);
  mred_kernel<<<512, 256, 0, stream>>>(Mpart, Msum);
  stepa_kernel<<<dim3(4, 4, 4), 256, 0, stream>>>(Wk, Msum, P);
  stepb_kernel<<<dim3(8, 4), 64, 0, stream>>>(P, Wv, Gsum);
  t3_kernel<<<dim3(8, 8, 4), 256, 0, stream>>>(Wq, Gsum, T3);
  wc_kernel<<<dim3(8, 8, 4), 64, 0, stream>>>(Wo, T3, WcT);
  out_kernel<<<1024, 256, 0, stream>>>(q, WcT, bo, Out);
}